// Round 11
// baseline (276.915 us; speedup 1.0000x reference)
//
#include <hip/hip_runtime.h>
#include <hip/hip_bf16.h>
#include <hip/hip_fp16.h>

#define NN    50000
#define NE    800000
#define ETOT  (NE + NN)
#define D     128
#define NB    ((NN + 255) / 256)   // scan blocks

typedef _Float16 f16x8 __attribute__((ext_vector_type(8)));
typedef float    f32x4 __attribute__((ext_vector_type(4)));

// fast tanh-gelu: gelu(x) = x - x/(exp(2z)+1), z = 0.79788456*(x+0.044715x^3)
__device__ __forceinline__ float gelu_fast(float x) {
    float x2 = x * x;
    float z2 = x * fmaf(x2, 0.07135483f, 1.5957691f);   // 2z
    float e  = __expf(z2);
    return x - __fdividef(x, e + 1.0f);
}

// ---------------- CSR build ----------------

__global__ void count_k(const int* __restrict__ dstarr, int* __restrict__ counts,
                        int* __restrict__ rank) {
    int e = blockIdx.x * blockDim.x + threadIdx.x;
    if (e >= ETOT) return;
    int d = (e < NE) ? dstarr[e] : (e - NE);
    rank[e] = atomicAdd(&counts[d], 1);
}

__global__ void scan1_k(const int* __restrict__ counts, int* __restrict__ blk_sums) {
    __shared__ int sm[4];
    int i = blockIdx.x * 256 + threadIdx.x;
    int v = (i < NN) ? counts[i] : 0;
    #pragma unroll
    for (int o = 32; o; o >>= 1) v += __shfl_xor(v, o);
    if ((threadIdx.x & 63) == 0) sm[threadIdx.x >> 6] = v;
    __syncthreads();
    if (threadIdx.x == 0) blk_sums[blockIdx.x] = sm[0] + sm[1] + sm[2] + sm[3];
}

__global__ void scan2_k(const int* __restrict__ blk_sums, int* __restrict__ blk_offs,
                        int* __restrict__ row_ptr) {
    if (threadIdx.x == 0 && blockIdx.x == 0) {
        int acc = 0;
        for (int b = 0; b < NB; ++b) { blk_offs[b] = acc; acc += blk_sums[b]; }
        row_ptr[NN] = acc;
    }
}

__global__ void scan3_k(const int* __restrict__ counts, const int* __restrict__ blk_offs,
                        int* __restrict__ row_ptr) {
    __shared__ int s[256];
    int t = threadIdx.x;
    int i = blockIdx.x * 256 + t;
    int v = (i < NN) ? counts[i] : 0;
    s[t] = v;
    __syncthreads();
    for (int off = 1; off < 256; off <<= 1) {
        int x = (t >= off) ? s[t - off] : 0;
        __syncthreads();
        s[t] += x;
        __syncthreads();
    }
    int excl = s[t] - v + blk_offs[blockIdx.x];
    if (i < NN) row_ptr[i] = excl;
}

__global__ void scatter2_k(const int* __restrict__ srcarr, const int* __restrict__ dstarr,
                           const int* __restrict__ rank, const int* __restrict__ row_ptr,
                           int* __restrict__ srcs) {
    int e = blockIdx.x * blockDim.x + threadIdx.x;
    if (e >= ETOT) return;
    int d, s;
    if (e < NE) { d = dstarr[e]; s = srcarr[e]; }
    else        { d = e - NE;    s = e - NE; }
    srcs[row_ptr[d] + rank[e]] = s;
}

// ------------- wasd: per layer, was[k]=sum_c W[k][c]*as[c], wad likewise -------------

__global__ void wasd_k(const float* __restrict__ W, const float* __restrict__ asrc,
                       const float* __restrict__ adst, float* __restrict__ wasd) {
    int l = blockIdx.x;
    int t = threadIdx.x;
    int k = t & 127, which = t >> 7;
    const float* wr = W + (size_t)l * D * D + (size_t)k * D;
    const float* av = (which ? adst : asrc) + (size_t)l * D;
    float s = 0.f;
    #pragma unroll 4
    for (int c = 0; c < D; ++c) s += wr[c] * av[c];
    wasd[l * 256 + which * 128 + k] = s;
}

// ------------- wt: W[l][k][c] fp32 -> WT[l][c][k] fp16 -------------

__global__ void wt_k(const float* __restrict__ W, __half* __restrict__ WT) {
    int l = blockIdx.y;
    int i = blockIdx.x * 256 + threadIdx.x;
    int k = i >> 7, c = i & 127;
    WT[(size_t)l * 16384 + (size_t)c * 128 + k] =
        __float2half_rn(W[(size_t)l * 16384 + (size_t)k * 128 + c]);
}

// ------------- xcvt: x -> fp16 table (flat convert) -------------

__global__ __launch_bounds__(256) void xcvt_k(
        const float* __restrict__ x, __half* __restrict__ xh) {
    int i = blockIdx.x * 256 + threadIdx.x;    // one float2 per thread
    float2 v = ((const float2*)x)[i];
    ((__half2*)xh)[i] = __floats2half2_rn(v.x, v.y);
}

// ------------- MFMA fp16 GEMM + fused alphas from input rows -----------------
// XPH output in HALVES layout: [2][NN][64] fp16. alphas(l) = TH(l) . wasd(l),
// computed by c0==0 blocks only (each input row read once there).

__global__ __launch_bounds__(256) void gemm_mfma_k(
        const __half* __restrict__ TH, const __half* __restrict__ WT,
        const float* __restrict__ wasd,
        __half* __restrict__ XPH, float* __restrict__ alpha_s, float* __restrict__ alpha_d) {
    __shared__ __half Bs[D * D];     // 32 KB, [c][k] with byte^((c&7)<<4) swizzle
    int t = threadIdx.x;
    #pragma unroll
    for (int it = 0; it < 8; ++it) {
        int b = it * 4096 + t * 16;
        int c = b >> 8;
        int swz = b ^ ((c & 7) << 4);
        *(uint4*)((char*)Bs + swz) = *(const uint4*)((const char*)WT + b);
    }
    __syncthreads();

    int w = t >> 6, lane = t & 63;
    int r0 = (blockIdx.x >> 1) * 256 + w * 64;
    int c0 = (blockIdx.x & 1) * 64;
    int lr = lane & 15, lg = lane >> 4;
    bool doalpha = (blockIdx.x & 1) == 0;

    f32x4 acc[4][4];
    #pragma unroll
    for (int i = 0; i < 4; ++i)
        #pragma unroll
        for (int j = 0; j < 4; ++j)
            acc[i][j] = (f32x4){0.f, 0.f, 0.f, 0.f};

    float ps[4] = {0, 0, 0, 0}, pd[4] = {0, 0, 0, 0};

    const char* abase = (const char*)TH;
    #pragma unroll
    for (int ks = 0; ks < 4; ++ks) {
        f16x8 bf[4];
        #pragma unroll
        for (int ct = 0; ct < 4; ++ct) {
            int c  = c0 + ct * 16 + lr;
            int kb = ks * 64 + lg * 16;
            int addr = c * 256 + (kb ^ ((c & 7) << 4));
            bf[ct] = *(const f16x8*)((const char*)Bs + addr);
        }
        // wasd slice for this lane's k-range (k = ks*32 + lg*8 .. +7)
        float4 s0, s1, d0, d1;
        if (doalpha) {
            const float* wsp = wasd + ks * 32 + lg * 8;
            s0 = *(const float4*)(wsp);       s1 = *(const float4*)(wsp + 4);
            d0 = *(const float4*)(wsp + 128); d1 = *(const float4*)(wsp + 132);
        }
        #pragma unroll
        for (int rt = 0; rt < 4; ++rt) {
            int row = r0 + rt * 16 + lr;
            int rc  = row < NN ? row : NN - 1;
            f16x8 af = *(const f16x8*)(abase + (size_t)rc * 256 + ks * 64 + lg * 16);
            if (doalpha) {
                float a0 = (float)af[0], a1 = (float)af[1], a2 = (float)af[2], a3 = (float)af[3];
                float a4 = (float)af[4], a5 = (float)af[5], a6 = (float)af[6], a7 = (float)af[7];
                ps[rt] += a0*s0.x + a1*s0.y + a2*s0.z + a3*s0.w
                        + a4*s1.x + a5*s1.y + a6*s1.z + a7*s1.w;
                pd[rt] += a0*d0.x + a1*d0.y + a2*d0.z + a3*d0.w
                        + a4*d1.x + a5*d1.y + a6*d1.z + a7*d1.w;
            }
            #pragma unroll
            for (int ct = 0; ct < 4; ++ct)
                acc[rt][ct] = __builtin_amdgcn_mfma_f32_16x16x32_f16(
                                  af, bf[ct], acc[rt][ct], 0, 0, 0);
        }
    }

    // C write -> halves table (half = c0>>6 is block-uniform)
    __half* xpt = XPH + (size_t)(c0 >> 6) * NN * 64;
    #pragma unroll
    for (int rt = 0; rt < 4; ++rt) {
        #pragma unroll
        for (int q = 0; q < 4; ++q) {
            int row = r0 + rt * 16 + lg * 4 + q;
            if (row < NN) {
                #pragma unroll
                for (int ct = 0; ct < 4; ++ct) {
                    int colh = ct * 16 + lr;
                    xpt[(size_t)row * 64 + colh] = __float2half_rn(acc[rt][ct][q]);
                }
            }
        }
    }

    // alpha reduce: sum over lg groups (lanes lr, lr+16, lr+32, lr+48)
    if (doalpha) {
        #pragma unroll
        for (int rt = 0; rt < 4; ++rt) {
            float p = ps[rt], dq = pd[rt];
            p  += __shfl_xor(p, 16);  p  += __shfl_xor(p, 32);
            dq += __shfl_xor(dq, 16); dq += __shfl_xor(dq, 32);
            int row = r0 + rt * 16 + lr;
            if (lane < 16 && row < NN) { alpha_s[row] = p; alpha_d[row] = dq; }
        }
    }
}

// ------- half-table aggregation: block handles 4 (node, half) units; XCD-pinned halves ---
// XPH: [2][NN][64] fp16. 8 lanes x 16B per edge row -> 8 edges in flight per wave.

template <int OUT32, int GELU>
__global__ __launch_bounds__(256) void agg_h_k(
        const int* __restrict__ row_ptr, const int* __restrict__ srcs,
        const float* __restrict__ alpha_s, const float* __restrict__ alpha_d,
        const __half* __restrict__ XPH, const float* __restrict__ bias,
        void* __restrict__ outp) {
    __shared__ float xch[4][64];      // 1 KB redistribution buffer
    int b = blockIdx.x;
    int xcd  = b & 7;
    int half = xcd >> 2;                          // XCD 0-3 -> half 0, 4-7 -> half 1
    int lblk = (b >> 3) * 4 + (xcd & 3);          // 0..12499
    int wv = threadIdx.x >> 6, lane = threadIdx.x & 63;
    int n = lblk * 4 + wv;
    int beg = row_ptr[n], end = row_ptr[n + 1], deg = end - beg;
    float ad = alpha_d[n];
    const __half* tab = XPH + (size_t)half * NN * 64;
    const char* tb = (const char*)tab;
    float fin;

    if (deg <= 64) {
        int sreg = 0;
        float e = -3.4e38f;
        if (lane < deg) {
            sreg = srcs[beg + lane];
            float v = alpha_s[sreg] + ad;
            e = v > 0.f ? v : 0.2f * v;
        }
        float m = e;
        #pragma unroll
        for (int o = 32; o; o >>= 1) m = fmaxf(m, __shfl_xor(m, o));
        float w = (lane < deg) ? __expf(e - m) : 0.f;
        float denom = w;
        #pragma unroll
        for (int o = 32; o; o >>= 1) denom += __shfl_xor(denom, o);

        int og = lane >> 3, qb = (lane & 7) << 4;
        float acc[8] = {0, 0, 0, 0, 0, 0, 0, 0};
        int dgr = (deg + 7) & ~7;
        int j = 0;
        #define GATHER8(JOFF)                                                    \
            {                                                                    \
                int ee = j + (JOFF) + og;                                        \
                int   ss = __shfl(sreg, ee); float ww = __shfl(w, ee);           \
                uint4 uu = *(const uint4*)(tb + ((ss << 7) + qb));               \
                union { uint4 u; __half2 h[4]; } U; U.u = uu;                    \
                float2 f0 = __half22float2(U.h[0]);                              \
                float2 f1 = __half22float2(U.h[1]);                              \
                float2 f2 = __half22float2(U.h[2]);                              \
                float2 f3 = __half22float2(U.h[3]);                              \
                acc[0] += ww*f0.x; acc[1] += ww*f0.y;                            \
                acc[2] += ww*f1.x; acc[3] += ww*f1.y;                            \
                acc[4] += ww*f2.x; acc[5] += ww*f2.y;                            \
                acc[6] += ww*f3.x; acc[7] += ww*f3.y;                            \
            }
        for (; j + 16 <= dgr; j += 16) {
            GATHER8(0) GATHER8(8)
        }
        for (; j < dgr; j += 8) {
            GATHER8(0)
        }
        #undef GATHER8
        #pragma unroll
        for (int f = 0; f < 8; ++f) {
            acc[f] += __shfl_xor(acc[f], 8);
            acc[f] += __shfl_xor(acc[f], 16);
            acc[f] += __shfl_xor(acc[f], 32);
        }
        // redistribute: lanes 0..7 own features lane*8..lane*8+7 -> 1 feature/lane
        if (lane < 8) {
            float4* p = (float4*)&xch[wv][lane * 8];
            p[0] = make_float4(acc[0], acc[1], acc[2], acc[3]);
            p[1] = make_float4(acc[4], acc[5], acc[6], acc[7]);
        }
        __asm__ volatile("s_waitcnt lgkmcnt(0)" ::: "memory");
        __builtin_amdgcn_sched_barrier(0);
        float inv = 1.f / (denom + 1e-16f);
        fin = xch[wv][lane] * inv;
    } else {
        // rare fallback (deg > 64): 3-pass; lane owns feature `lane` of this half
        float m = -3.4e38f;
        for (int i = beg + lane; i < end; i += 64) {
            int s = srcs[i];
            float v = alpha_s[s] + ad; v = v > 0.f ? v : 0.2f * v;
            m = fmaxf(m, v);
        }
        #pragma unroll
        for (int o = 32; o; o >>= 1) m = fmaxf(m, __shfl_xor(m, o));
        float denom = 0.f;
        for (int i = beg + lane; i < end; i += 64) {
            int s = srcs[i];
            float v = alpha_s[s] + ad; v = v > 0.f ? v : 0.2f * v;
            denom += __expf(v - m);
        }
        #pragma unroll
        for (int o = 32; o; o >>= 1) denom += __shfl_xor(denom, o);
        float acc = 0.f;
        for (int i = beg; i < end; ++i) {
            int s = srcs[i];
            float v = alpha_s[s] + ad; v = v > 0.f ? v : 0.2f * v;
            float wgt = __expf(v - m);
            acc += wgt * __half2float(tab[(size_t)s * 64 + lane]);
        }
        fin = acc / (denom + 1e-16f);
    }

    // epilogue: lane owns feature half*64+lane
    fin += bias[half * 64 + lane];
    if (GELU) fin = gelu_fast(fin);
    if (OUT32) ((float*)outp)[(size_t)n * D + half * 64 + lane] = fin;
    else       ((__half*)outp)[(size_t)n * D + half * 64 + lane] = __float2half_rn(fin);
}

// ---------------- launch ----------------

extern "C" void kernel_launch(void* const* d_in, const int* in_sizes, int n_in,
                              void* d_out, int out_size, void* d_ws, size_t ws_size,
                              hipStream_t stream) {
    const float* x    = (const float*)d_in[0];
    const int*   ei   = (const int*)d_in[1];
    const float* W    = (const float*)d_in[2];
    const float* asrc = (const float*)d_in[3];
    const float* adst = (const float*)d_in[4];
    const float* bias = (const float*)d_in[5];
    float* out = (float*)d_out;

    const int* src_arr = ei;
    const int* dst_arr = ei + NE;

    char* ws = (char*)d_ws;
    size_t off = 0;
    auto alloc = [&](size_t bytes) { char* p = ws + off; off += (bytes + 255) & ~(size_t)255; return p; };
    __half* th_a    = (__half*)alloc((size_t)NN * D * sizeof(__half));
    __half* th_b    = (__half*)alloc((size_t)NN * D * sizeof(__half));
    __half* xph     = (__half*)alloc((size_t)2 * NN * 64 * sizeof(__half));  // halves
    __half* wt      = (__half*)alloc((size_t)3 * D * D * sizeof(__half));
    float*  as_a    = (float*)alloc(NN * sizeof(float));
    float*  ad_a    = (float*)alloc(NN * sizeof(float));
    float*  wasd    = (float*)alloc(3 * 256 * sizeof(float));
    int* counts    = (int*)alloc(NN * sizeof(int));
    int* row_ptr   = (int*)alloc((NN + 1) * sizeof(int));
    int* rank      = (int*)alloc((size_t)ETOT * sizeof(int));
    int* blk_sums  = (int*)alloc(NB * sizeof(int));
    int* blk_offs  = (int*)alloc(NB * sizeof(int));
    int* srcs      = (int*)alloc((size_t)ETOT * sizeof(int));
    (void)ws_size; (void)in_sizes; (void)n_in; (void)out_size;

    // CSR build (by dst), includes self loops — atomic-free scatter via ranks
    hipMemsetAsync(counts, 0, NN * sizeof(int), stream);
    int eb = (ETOT + 255) / 256;
    count_k<<<eb, 256, 0, stream>>>(dst_arr, counts, rank);
    scan1_k<<<NB, 256, 0, stream>>>(counts, blk_sums);
    scan2_k<<<1, 64, 0, stream>>>(blk_sums, blk_offs, row_ptr);
    scan3_k<<<NB, 256, 0, stream>>>(counts, blk_offs, row_ptr);
    scatter2_k<<<eb, 256, 0, stream>>>(src_arr, dst_arr, rank, row_ptr, srcs);

    // prep
    wasd_k<<<3, 256, 0, stream>>>(W, asrc, adst, wasd);
    wt_k<<<dim3(64, 3), 256, 0, stream>>>(W, wt);
    xcvt_k<<<NN * 64 / 256, 256, 0, stream>>>(x, th_a);

    int gb = 2 * ((NN + 255) / 256);   // 392
    int ab = 2 * (NN / 4);             // 25000 (node x half units / 4 per block)

    // layer 0
    gemm_mfma_k<<<gb, 256, 0, stream>>>(th_a, wt, wasd, xph, as_a, ad_a);
    agg_h_k<0, 1><<<ab, 256, 0, stream>>>(row_ptr, srcs, as_a, ad_a, xph, bias, th_b);
    // layer 1
    gemm_mfma_k<<<gb, 256, 0, stream>>>(th_b, wt + 16384, wasd + 256, xph, as_a, ad_a);
    agg_h_k<0, 1><<<ab, 256, 0, stream>>>(row_ptr, srcs, as_a, ad_a, xph, bias + D, th_a);
    // layer 2
    gemm_mfma_k<<<gb, 256, 0, stream>>>(th_a, wt + 32768, wasd + 512, xph, as_a, ad_a);
    agg_h_k<1, 0><<<ab, 256, 0, stream>>>(row_ptr, srcs, as_a, ad_a, xph, bias + 2 * D, out);
}

// Round 12
// 212.685 us; speedup vs baseline: 1.3020x; 1.3020x over previous
//
#include <hip/hip_runtime.h>
#include <hip/hip_bf16.h>
#include <hip/hip_fp16.h>

#define NN    50000
#define NE    800000
#define ETOT  (NE + NN)
#define D     128
#define NB    ((NN + 255) / 256)     // 196 scan blocks
#define EB    ((ETOT + 255) / 256)   // 3321 count blocks
#define XB    ((NN * 64) / 256)      // 12500 xcvt blocks

typedef _Float16 f16x8 __attribute__((ext_vector_type(8)));
typedef float    f32x4 __attribute__((ext_vector_type(4)));

// fast tanh-gelu: gelu(x) = x - x/(exp(2z)+1), z = 0.79788456*(x+0.044715x^3)
__device__ __forceinline__ float gelu_fast(float x) {
    float x2 = x * x;
    float z2 = x * fmaf(x2, 0.07135483f, 1.5957691f);   // 2z
    float e  = __expf(z2);
    return x - __fdividef(x, e + 1.0f);
}

// ---------------- fused prep: count+rank | x->fp16 | W^T fp16 | wasd ----------------

__global__ __launch_bounds__(256) void prep_k(
        const int* __restrict__ dst_arr, int* __restrict__ counts, int* __restrict__ rank,
        const float* __restrict__ x, __half* __restrict__ xh,
        const float* __restrict__ W, __half* __restrict__ WT,
        const float* __restrict__ asrc, const float* __restrict__ adst,
        float* __restrict__ wasd) {
    int b = blockIdx.x, t = threadIdx.x;
    if (b < EB) {
        int e = b * 256 + t;
        if (e < ETOT) {
            int d = (e < NE) ? dst_arr[e] : (e - NE);
            rank[e] = atomicAdd(&counts[d], 1);
        }
    } else if (b < EB + XB) {
        int i = (b - EB) * 256 + t;
        float2 v = ((const float2*)x)[i];
        ((__half2*)xh)[i] = __floats2half2_rn(v.x, v.y);
    } else if (b < EB + XB + 192) {
        int i = (b - EB - XB) * 256 + t;     // 0..49151
        int l = i >> 14, r = i & 16383;
        int k = r >> 7, c = r & 127;
        WT[(size_t)l * 16384 + (size_t)c * 128 + k] =
            __float2half_rn(W[(size_t)l * 16384 + (size_t)k * 128 + c]);
    } else {
        int l = b - EB - XB - 192;           // 0..2
        int k = t & 127, which = t >> 7;
        const float* wr = W + (size_t)l * 16384 + (size_t)k * 128;
        const float* av = (which ? adst : asrc) + (size_t)l * 128;
        float s = 0.f;
        #pragma unroll 4
        for (int c = 0; c < 128; ++c) s += wr[c] * av[c];
        wasd[l * 256 + which * 128 + k] = s;
    }
}

// ---------------- scans ----------------

__global__ void scan1_k(const int* __restrict__ counts, int* __restrict__ blk_sums) {
    __shared__ int sm[4];
    int i = blockIdx.x * 256 + threadIdx.x;
    int v = (i < NN) ? counts[i] : 0;
    #pragma unroll
    for (int o = 32; o; o >>= 1) v += __shfl_xor(v, o);
    if ((threadIdx.x & 63) == 0) sm[threadIdx.x >> 6] = v;
    __syncthreads();
    if (threadIdx.x == 0) blk_sums[blockIdx.x] = sm[0] + sm[1] + sm[2] + sm[3];
}

// fused scan2+scan3: each block computes its own offset from blk_sums
__global__ void scan23_k(const int* __restrict__ counts, const int* __restrict__ blk_sums,
                         int* __restrict__ row_ptr) {
    __shared__ int s[256];
    __shared__ int boff_sh;
    int t = threadIdx.x, bid = blockIdx.x;
    if (t < 64) {
        int acc = 0;
        for (int i = t; i < bid; i += 64) acc += blk_sums[i];
        #pragma unroll
        for (int o = 32; o; o >>= 1) acc += __shfl_xor(acc, o);
        if (t == 0) boff_sh = acc;
    }
    __syncthreads();
    int boff = boff_sh;
    int i = bid * 256 + t;
    int v = (i < NN) ? counts[i] : 0;
    s[t] = v;
    __syncthreads();
    for (int off = 1; off < 256; off <<= 1) {
        int x = (t >= off) ? s[t - off] : 0;
        __syncthreads();
        s[t] += x;
        __syncthreads();
    }
    int excl = s[t] - v + boff;
    if (i < NN) row_ptr[i] = excl;
    if (bid == NB - 1 && t == 255) row_ptr[NN] = s[255] + boff;   // == ETOT
}

// atomic-free scatter: pos = row_ptr[dst] + rank
__global__ void scatter2_k(const int* __restrict__ srcarr, const int* __restrict__ dstarr,
                           const int* __restrict__ rank, const int* __restrict__ row_ptr,
                           int* __restrict__ srcs) {
    int e = blockIdx.x * blockDim.x + threadIdx.x;
    if (e >= ETOT) return;
    int d, s;
    if (e < NE) { d = dstarr[e]; s = srcarr[e]; }
    else        { d = e - NE;    s = e - NE; }
    srcs[row_ptr[d] + rank[e]] = s;
}

// ------------- MFMA fp16 GEMM + fused alphas (alphas = TH . wasd, c0==0 blocks) -------

__global__ __launch_bounds__(256) void gemm_mfma_k(
        const __half* __restrict__ TH, const __half* __restrict__ WT,
        const float* __restrict__ wasd,
        __half* __restrict__ XP, float* __restrict__ alpha_s, float* __restrict__ alpha_d) {
    __shared__ __half Bs[D * D];     // 32 KB, [c][k] with byte^((c&7)<<4) swizzle
    int t = threadIdx.x;
    #pragma unroll
    for (int it = 0; it < 8; ++it) {
        int b = it * 4096 + t * 16;
        int c = b >> 8;
        int swz = b ^ ((c & 7) << 4);
        *(uint4*)((char*)Bs + swz) = *(const uint4*)((const char*)WT + b);
    }
    __syncthreads();

    int w = t >> 6, lane = t & 63;
    int r0 = (blockIdx.x >> 1) * 256 + w * 64;
    int c0 = (blockIdx.x & 1) * 64;
    int lr = lane & 15, lg = lane >> 4;
    bool doalpha = (blockIdx.x & 1) == 0;

    f32x4 acc[4][4];
    #pragma unroll
    for (int i = 0; i < 4; ++i)
        #pragma unroll
        for (int j = 0; j < 4; ++j)
            acc[i][j] = (f32x4){0.f, 0.f, 0.f, 0.f};

    float ps[4] = {0, 0, 0, 0}, pd[4] = {0, 0, 0, 0};

    const char* abase = (const char*)TH;
    #pragma unroll
    for (int ks = 0; ks < 4; ++ks) {
        f16x8 bf[4];
        #pragma unroll
        for (int ct = 0; ct < 4; ++ct) {
            int c  = c0 + ct * 16 + lr;
            int kb = ks * 64 + lg * 16;
            int addr = c * 256 + (kb ^ ((c & 7) << 4));
            bf[ct] = *(const f16x8*)((const char*)Bs + addr);
        }
        float4 s0, s1, d0, d1;
        if (doalpha) {
            const float* wsp = wasd + ks * 32 + lg * 8;
            s0 = *(const float4*)(wsp);       s1 = *(const float4*)(wsp + 4);
            d0 = *(const float4*)(wsp + 128); d1 = *(const float4*)(wsp + 132);
        }
        #pragma unroll
        for (int rt = 0; rt < 4; ++rt) {
            int row = r0 + rt * 16 + lr;
            int rc  = row < NN ? row : NN - 1;
            f16x8 af = *(const f16x8*)(abase + (size_t)rc * 256 + ks * 64 + lg * 16);
            if (doalpha) {
                float a0 = (float)af[0], a1 = (float)af[1], a2 = (float)af[2], a3 = (float)af[3];
                float a4 = (float)af[4], a5 = (float)af[5], a6 = (float)af[6], a7 = (float)af[7];
                ps[rt] += a0*s0.x + a1*s0.y + a2*s0.z + a3*s0.w
                        + a4*s1.x + a5*s1.y + a6*s1.z + a7*s1.w;
                pd[rt] += a0*d0.x + a1*d0.y + a2*d0.z + a3*d0.w
                        + a4*d1.x + a5*d1.y + a6*d1.z + a7*d1.w;
            }
            #pragma unroll
            for (int ct = 0; ct < 4; ++ct)
                acc[rt][ct] = __builtin_amdgcn_mfma_f32_16x16x32_f16(
                                  af, bf[ct], acc[rt][ct], 0, 0, 0);
        }
    }

    #pragma unroll
    for (int rt = 0; rt < 4; ++rt) {
        #pragma unroll
        for (int q = 0; q < 4; ++q) {
            int row = r0 + rt * 16 + lg * 4 + q;
            if (row < NN) {
                #pragma unroll
                for (int ct = 0; ct < 4; ++ct) {
                    int col = c0 + ct * 16 + lr;
                    XP[(size_t)row * D + col] = __float2half_rn(acc[rt][ct][q]);
                }
            }
        }
    }

    if (doalpha) {
        #pragma unroll
        for (int rt = 0; rt < 4; ++rt) {
            float p = ps[rt], dq = pd[rt];
            p  += __shfl_xor(p, 16);  p  += __shfl_xor(p, 32);
            dq += __shfl_xor(dq, 16); dq += __shfl_xor(dq, 32);
            int row = r0 + rt * 16 + lr;
            if (lane < 16 && row < NN) { alpha_s[row] = p; alpha_d[row] = dq; }
        }
    }
}

// ------- aggregation: gather fp16 [NN][128] rows, pipelined loads, 2-feature epilogue ----

template <int OUT32, int GELU>
__global__ __launch_bounds__(256) void agg_u_k(
        const int* __restrict__ row_ptr, const int* __restrict__ srcs,
        const float* __restrict__ alpha_s, const float* __restrict__ alpha_d,
        const __half* __restrict__ XPH, const float* __restrict__ bias,
        void* __restrict__ outp) {
    __shared__ float xch[4][128];     // 2 KB redistribution buffer
    int wv = threadIdx.x >> 6;
    int n = (blockIdx.x * blockDim.x + threadIdx.x) >> 6;
    int lane = threadIdx.x & 63;
    int beg = row_ptr[n], end = row_ptr[n + 1], deg = end - beg;
    float ad = alpha_d[n];
    int qw = lane >> 4, q = lane & 15;

    float2 fin;   // this lane's features (2*lane, 2*lane+1), normalized (pre-bias)

    if (deg <= 64) {
        int sreg = 0;
        float e = -3.4e38f;
        if (lane < deg) {
            sreg = srcs[beg + lane];
            float v = alpha_s[sreg] + ad;
            e = v > 0.f ? v : 0.2f * v;
        }
        float m = e;
        #pragma unroll
        for (int o = 32; o; o >>= 1) m = fmaxf(m, __shfl_xor(m, o));
        float w = (lane < deg) ? __expf(e - m) : 0.f;
        float denom = w;
        #pragma unroll
        for (int o = 32; o; o >>= 1) denom += __shfl_xor(denom, o);

        float acc[8] = {0,0,0,0,0,0,0,0};
        int dgr = (deg + 3) & ~3;
        const char* xb = (const char*)XPH;
        int qb = q << 4;
        int j = 0;
        #define PROC(UU, WW)                                                     \
            {                                                                    \
                union { uint4 u; __half2 h[4]; } U; U.u = (UU);                  \
                float2 f0 = __half22float2(U.h[0]);                              \
                float2 f1 = __half22float2(U.h[1]);                              \
                float2 f2 = __half22float2(U.h[2]);                              \
                float2 f3 = __half22float2(U.h[3]);                              \
                acc[0] += (WW)*f0.x; acc[1] += (WW)*f0.y;                        \
                acc[2] += (WW)*f1.x; acc[3] += (WW)*f1.y;                        \
                acc[4] += (WW)*f2.x; acc[5] += (WW)*f2.y;                        \
                acc[6] += (WW)*f3.x; acc[7] += (WW)*f3.y;                        \
            }
        for (; j + 16 <= dgr; j += 16) {
            // batch the shfl broadcasts, then all 4 loads in flight, then compute
            int   s0 = __shfl(sreg, j + qw);       float w0 = __shfl(w, j + qw);
            int   s1 = __shfl(sreg, j + 4 + qw);   float w1 = __shfl(w, j + 4 + qw);
            int   s2 = __shfl(sreg, j + 8 + qw);   float w2 = __shfl(w, j + 8 + qw);
            int   s3 = __shfl(sreg, j + 12 + qw);  float w3 = __shfl(w, j + 12 + qw);
            uint4 u0 = *(const uint4*)(xb + ((s0 << 8) + qb));
            uint4 u1 = *(const uint4*)(xb + ((s1 << 8) + qb));
            uint4 u2 = *(const uint4*)(xb + ((s2 << 8) + qb));
            uint4 u3 = *(const uint4*)(xb + ((s3 << 8) + qb));
            PROC(u0, w0) PROC(u1, w1) PROC(u2, w2) PROC(u3, w3)
        }
        for (; j < dgr; j += 4) {
            int   s0 = __shfl(sreg, j + qw);
            float w0 = __shfl(w, j + qw);
            uint4 u0 = *(const uint4*)(xb + ((s0 << 8) + qb));
            PROC(u0, w0)
        }
        #undef PROC
        #pragma unroll
        for (int f = 0; f < 8; ++f) {
            acc[f] += __shfl_xor(acc[f], 16);
            acc[f] += __shfl_xor(acc[f], 32);
        }
        // redistribute: lanes<16 own features q*8+f -> every lane owns (2l, 2l+1)
        if (lane < 16) {
            float4* p = (float4*)&xch[wv][q * 8];
            p[0] = make_float4(acc[0], acc[1], acc[2], acc[3]);
            p[1] = make_float4(acc[4], acc[5], acc[6], acc[7]);
        }
        __asm__ volatile("s_waitcnt lgkmcnt(0)" ::: "memory");
        __builtin_amdgcn_sched_barrier(0);
        float2 a2 = *(const float2*)&xch[wv][2 * lane];
        float inv = 1.f / (denom + 1e-16f);
        fin.x = a2.x * inv;
        fin.y = a2.y * inv;
    } else {
        // rare fallback (deg > 64): 3-pass, directly in 2-feature layout
        float m = -3.4e38f;
        for (int i = beg + lane; i < end; i += 64) {
            int s = srcs[i];
            float v = alpha_s[s] + ad; v = v > 0.f ? v : 0.2f * v;
            m = fmaxf(m, v);
        }
        #pragma unroll
        for (int o = 32; o; o >>= 1) m = fmaxf(m, __shfl_xor(m, o));
        float denom = 0.f;
        for (int i = beg + lane; i < end; i += 64) {
            int s = srcs[i];
            float v = alpha_s[s] + ad; v = v > 0.f ? v : 0.2f * v;
            denom += __expf(v - m);
        }
        #pragma unroll
        for (int o = 32; o; o >>= 1) denom += __shfl_xor(denom, o);
        float2 acc = {0.f, 0.f};
        for (int i = beg; i < end; ++i) {
            int s = srcs[i];
            float v = alpha_s[s] + ad; v = v > 0.f ? v : 0.2f * v;
            float wgt = __expf(v - m);
            union { unsigned int x; __half2 h; } U;
            U.x = ((const unsigned int*)(XPH + (size_t)s * D))[lane];
            float2 f = __half22float2(U.h);
            acc.x += wgt * f.x; acc.y += wgt * f.y;
        }
        float inv = 1.f / (denom + 1e-16f);
        fin.x = acc.x * inv;
        fin.y = acc.y * inv;
    }

    // ---- epilogue: every lane handles features (2*lane, 2*lane+1) ----
    float2 b2 = ((const float2*)bias)[lane];
    fin.x += b2.x;
    fin.y += b2.y;
    if (GELU) { fin.x = gelu_fast(fin.x); fin.y = gelu_fast(fin.y); }

    if (OUT32) {
        ((float2*)((float*)outp + (size_t)n * D))[lane] = fin;
    } else {
        ((__half2*)((__half*)outp + (size_t)n * D))[lane] = __floats2half2_rn(fin.x, fin.y);
    }
}

// ---------------- launch ----------------

extern "C" void kernel_launch(void* const* d_in, const int* in_sizes, int n_in,
                              void* d_out, int out_size, void* d_ws, size_t ws_size,
                              hipStream_t stream) {
    const float* x    = (const float*)d_in[0];
    const int*   ei   = (const int*)d_in[1];
    const float* W    = (const float*)d_in[2];
    const float* asrc = (const float*)d_in[3];
    const float* adst = (const float*)d_in[4];
    const float* bias = (const float*)d_in[5];
    float* out = (float*)d_out;

    const int* src_arr = ei;
    const int* dst_arr = ei + NE;

    char* ws = (char*)d_ws;
    size_t off = 0;
    auto alloc = [&](size_t bytes) { char* p = ws + off; off += (bytes + 255) & ~(size_t)255; return p; };
    __half* th_a    = (__half*)alloc((size_t)NN * D * sizeof(__half));
    __half* th_b    = (__half*)alloc((size_t)NN * D * sizeof(__half));
    __half* xph     = (__half*)alloc((size_t)NN * D * sizeof(__half));
    __half* wt      = (__half*)alloc((size_t)3 * D * D * sizeof(__half));
    float*  as_a    = (float*)alloc(NN * sizeof(float));
    float*  ad_a    = (float*)alloc(NN * sizeof(float));
    float*  wasd    = (float*)alloc(3 * 256 * sizeof(float));
    int* counts    = (int*)alloc(NN * sizeof(int));
    int* row_ptr   = (int*)alloc((NN + 1) * sizeof(int));
    int* rank      = (int*)alloc((size_t)ETOT * sizeof(int));
    int* blk_sums  = (int*)alloc(NB * sizeof(int));
    int* srcs      = (int*)alloc((size_t)ETOT * sizeof(int));
    (void)ws_size; (void)in_sizes; (void)n_in; (void)out_size;

    // phase 1: counts zero, then fused prep (count+rank | xcvt | wt | wasd)
    hipMemsetAsync(counts, 0, NN * sizeof(int), stream);
    prep_k<<<EB + XB + 192 + 3, 256, 0, stream>>>(dst_arr, counts, rank,
                                                  x, th_a, W, wt, asrc, adst, wasd);
    scan1_k<<<NB, 256, 0, stream>>>(counts, blk_sums);
    scan23_k<<<NB, 256, 0, stream>>>(counts, blk_sums, row_ptr);
    scatter2_k<<<EB, 256, 0, stream>>>(src_arr, dst_arr, rank, row_ptr, srcs);

    int gb = 2 * ((NN + 255) / 256);   // 392
    int ab = NN / 4;                   // 12500

    // layer 0
    gemm_mfma_k<<<gb, 256, 0, stream>>>(th_a, wt, wasd, xph, as_a, ad_a);
    agg_u_k<0, 1><<<ab, 256, 0, stream>>>(row_ptr, srcs, as_a, ad_a, xph, bias, th_b);
    // layer 1
    gemm_mfma_k<<<gb, 256, 0, stream>>>(th_b, wt + 16384, wasd + 256, xph, as_a, ad_a);
    agg_u_k<0, 1><<<ab, 256, 0, stream>>>(row_ptr, srcs, as_a, ad_a, xph, bias + D, th_a);
    // layer 2
    gemm_mfma_k<<<gb, 256, 0, stream>>>(th_a, wt + 32768, wasd + 512, xph, as_a, ad_a);
    agg_u_k<1, 0><<<ab, 256, 0, stream>>>(row_ptr, srcs, as_a, ad_a, xph, bias + 2 * D, out);
}